// Round 1
// baseline (392.887 us; speedup 1.0000x reference)
//
#include <hip/hip_runtime.h>

typedef __attribute__((ext_vector_type(8))) short bf16x8;
typedef __attribute__((ext_vector_type(4))) float f32x4;
typedef unsigned short u16;
typedef unsigned int u32;

#define NTOK 144
#define CDIM 192
#define NH 6
#define CH 32
#define C3 576
#define NWIN 64
#define WLON 15
#define SCALE 0.17677669529663687f

// ws layout (bytes)
#define OFF_W1T  0u            // 576*192*2 = 221184
#define OFF_W2T  221184u       // 192*192*2 = 73728
#define OFF_COMB 294912u       // 64*6*20736*2 = 15925248
#define OFF_Q    16220160u     // 960*6*144*32*2 = 53084160
#define OFF_K    69304320u
#define OFF_V    122388480u

__device__ __forceinline__ u16 f2b(float f){
  u32 u = __float_as_uint(f);
  u32 r = u + 0x7FFFu + ((u >> 16) & 1u);   // RNE
  return (u16)(r >> 16);
}
__device__ __forceinline__ float b2f(u16 u){
  return __uint_as_float(((u32)u) << 16);
}
__device__ __forceinline__ u32 pk2(float a, float b){
  return (u32)f2b(a) | ((u32)f2b(b) << 16);
}

// ---------------- prep: transpose weights to bf16 (B-operand wants k-contiguous rows)
extern "C" __global__ __launch_bounds__(256) void prep_weights(
    const float* __restrict__ w1, const float* __restrict__ w2,
    u16* __restrict__ w1t, u16* __restrict__ w2t){
  int idx = blockIdx.x * 256 + threadIdx.x;
  if (idx < CDIM * C3){ int k = idx / C3;  int c = idx - k * C3;  w1t[c * CDIM + k] = f2b(w1[idx]); }
  if (idx < CDIM * CDIM){ int k = idx / CDIM; int c = idx - k * CDIM; w2t[c * CDIM + k] = f2b(w2[idx]); }
}

// ---------------- prep: comb[nw][h][i][j] = bias_table[pidx[i*144+j]][nw][h] + mask[nw*15][i][j]
// (mask is ww-independent by construction: the shift split has no w cut)
extern "C" __global__ __launch_bounds__(256) void prep_comb(
    const float* __restrict__ bt, const float* __restrict__ mask,
    const int* __restrict__ pidx, u16* __restrict__ comb){
  int nwh = blockIdx.x;                 // 0..383 = nw*6+h
  int nw = nwh / NH, h = nwh - nw * NH;
  int e = blockIdx.y * 256 + threadIdx.x;   // 0..20735
  int pi = pidx[e];
  float v = bt[((size_t)pi * NWIN + nw) * NH + h]
          + mask[(size_t)(nw * WLON) * (NTOK * NTOK) + e];
  comb[(size_t)nwh * (NTOK * NTOK) + e] = f2b(v);
}

// ---------------- K1: qkv = x @ w1 + b1 ; scatter q*scale,k,v -> [b][h][n][ch] bf16
#define APAD 200   // row stride (bf16) for 192-K tiles: 400B rows -> (row*25+k0)%8 covers all 8 bank-groups
extern "C" __global__ __launch_bounds__(256) void qkv_gemm(
    const float* __restrict__ x, const u16* __restrict__ w1t, const float* __restrict__ b1,
    u16* __restrict__ qw, u16* __restrict__ kw, u16* __restrict__ vw){
  __shared__ u16 Al[128 * APAD];
  __shared__ u16 Bl[64 * APAD];
  const int tid = threadIdx.x;
  const size_t row0 = (size_t)blockIdx.x * 128;

  { // stage A: 128x192 fp32 -> bf16, 2 threads/row
    int r = tid >> 1, half = tid & 1;
    const float* src = x + (row0 + r) * CDIM + half * 96;
    u16* dst = Al + r * APAD + half * 96;
    #pragma unroll
    for (int i = 0; i < 96; i += 8){
      float4 f0 = *reinterpret_cast<const float4*>(src + i);
      float4 f1 = *reinterpret_cast<const float4*>(src + i + 4);
      uint4 pk; pk.x = pk2(f0.x, f0.y); pk.y = pk2(f0.z, f0.w);
      pk.z = pk2(f1.x, f1.y); pk.w = pk2(f1.z, f1.w);
      *reinterpret_cast<uint4*>(dst + i) = pk;
    }
  }
  const int wid = tid >> 6, lane = tid & 63;
  const int wm = (wid >> 1) * 64, wn = (wid & 1) * 32;
  const int l15 = lane & 15, l4 = lane >> 4;
  const f32x4 zz = {0.f, 0.f, 0.f, 0.f};

  for (int nt = 0; nt < 9; ++nt){
    __syncthreads();       // Bl free (prev compute done); A visible on nt=0
    { // stage B: 64 rows of w1t (192 bf16 each), 4 threads/row
      int r = tid >> 2, qq = tid & 3;
      const u16* src = w1t + (size_t)(nt * 64 + r) * CDIM + qq * 48;
      u16* dst = Bl + r * APAD + qq * 48;
      #pragma unroll
      for (int i = 0; i < 48; i += 8)
        *reinterpret_cast<uint4*>(dst + i) = *reinterpret_cast<const uint4*>(src + i);
    }
    __syncthreads();

    f32x4 acc[4][2];
    #pragma unroll
    for (int mf = 0; mf < 4; ++mf){ acc[mf][0] = zz; acc[mf][1] = zz; }
    #pragma unroll
    for (int kk = 0; kk < 6; ++kk){
      bf16x8 av[4], bv[2];
      #pragma unroll
      for (int mf = 0; mf < 4; ++mf)
        av[mf] = *reinterpret_cast<const bf16x8*>(Al + (wm + mf * 16 + l15) * APAD + kk * 32 + l4 * 8);
      #pragma unroll
      for (int nf = 0; nf < 2; ++nf)
        bv[nf] = *reinterpret_cast<const bf16x8*>(Bl + (wn + nf * 16 + l15) * APAD + kk * 32 + l4 * 8);
      #pragma unroll
      for (int mf = 0; mf < 4; ++mf)
        #pragma unroll
        for (int nf = 0; nf < 2; ++nf)
          acc[mf][nf] = __builtin_amdgcn_mfma_f32_16x16x32_bf16(av[mf], bv[nf], acc[mf][nf], 0, 0, 0);
    }
    // epilogue: c -> (which, h, ch); q gets *scale (after +b1, matching reference)
    #pragma unroll
    for (int nf = 0; nf < 2; ++nf){
      int c = nt * 64 + wn + nf * 16 + l15;
      int which = c / CDIM;
      int rem = c - which * CDIM;
      int hh = rem >> 5, chh = rem & 31;
      float bias = b1[c];
      float mult = (which == 0) ? SCALE : 1.0f;
      u16* base = (which == 0) ? qw : ((which == 1) ? kw : vw);
      #pragma unroll
      for (int mf = 0; mf < 4; ++mf){
        #pragma unroll
        for (int r = 0; r < 4; ++r){
          int t = (int)row0 + wm + mf * 16 + l4 * 4 + r;
          int bwin = t / NTOK;
          int n = t - bwin * NTOK;
          float v = (acc[mf][nf][r] + bias) * mult;
          base[(((size_t)bwin * NH + hh) * NTOK + n) * CH + chh] = f2b(v);
        }
      }
    }
  }
}

// ---------------- K2: per (window, head) attention; stash bf16 result in upper half of d_out rows
#define QKPAD 40    // 80B rows: (5r+k0)%8 hits all groups -> conflict-free b128
#define VPPAD 168   // 336B rows: (5r+k0)%8 likewise
#define OFF_VT 0
#define OFF_QL 10752
#define OFF_KL 22272
#define OFF_PL 10752     // Pl overlaps Ql+Kl (both dead after S phase)
#define SMEM_BYTES 59136
extern "C" __global__ __launch_bounds__(192) void attn_kernel(
    const u16* __restrict__ qw, const u16* __restrict__ kw, const u16* __restrict__ vw,
    const u16* __restrict__ comb, float* outbuf){
  __shared__ char smem[SMEM_BYTES];
  u16* Vt = (u16*)(smem + OFF_VT);
  u16* Ql = (u16*)(smem + OFF_QL);
  u16* Kl = (u16*)(smem + OFF_KL);
  u16* Pl = (u16*)(smem + OFF_PL);
  const int tid = threadIdx.x;
  const int bh = blockIdx.x;
  const int b = bh / NH, h = bh - (bh / NH) * NH;
  const size_t base = ((size_t)b * NH + h) * (NTOK * CH);

  // stage Q, K as [token][ch] (row stride 40)
  #pragma unroll
  for (int i = 0; i < 3; ++i){
    int chunk = tid + i * 192;          // 576 x 16B chunks
    int r = chunk >> 2, c4 = chunk & 3;
    *reinterpret_cast<uint4*>(Ql + r * QKPAD + c4 * 8) =
        *reinterpret_cast<const uint4*>(qw + base + r * CH + c4 * 8);
    *reinterpret_cast<uint4*>(Kl + r * QKPAD + c4 * 8) =
        *reinterpret_cast<const uint4*>(kw + base + r * CH + c4 * 8);
  }
  // stage V transposed: Vt[ch][token]
  #pragma unroll
  for (int i = 0; i < 3; ++i){
    int chunk = tid + i * 192;
    int tok = chunk >> 2, c4 = chunk & 3;
    uint4 dv = *reinterpret_cast<const uint4*>(vw + base + tok * CH + c4 * 8);
    int ch0 = c4 * 8;
    Vt[(ch0 + 0) * VPPAD + tok] = (u16)(dv.x & 0xFFFF);
    Vt[(ch0 + 1) * VPPAD + tok] = (u16)(dv.x >> 16);
    Vt[(ch0 + 2) * VPPAD + tok] = (u16)(dv.y & 0xFFFF);
    Vt[(ch0 + 3) * VPPAD + tok] = (u16)(dv.y >> 16);
    Vt[(ch0 + 4) * VPPAD + tok] = (u16)(dv.z & 0xFFFF);
    Vt[(ch0 + 5) * VPPAD + tok] = (u16)(dv.z >> 16);
    Vt[(ch0 + 6) * VPPAD + tok] = (u16)(dv.w & 0xFFFF);
    Vt[(ch0 + 7) * VPPAD + tok] = (u16)(dv.w >> 16);
  }
  // zero V K-pad (tokens 144..159) so PV pad contributes exact 0 (never NaN)
  for (int e = tid; e < 32 * 16; e += 192){
    int ch = e >> 4, c = 144 + (e & 15);
    Vt[ch * VPPAD + c] = 0;
  }
  __syncthreads();

  const int wv = tid >> 6, lane = tid & 63, l15 = lane & 15, l4 = lane >> 4;
  const f32x4 zz = {0.f, 0.f, 0.f, 0.f};

  // S = q @ k^T  (K=32 -> single MFMA step per 16x16 tile)
  bf16x8 aq[3];
  #pragma unroll
  for (int mi = 0; mi < 3; ++mi)
    aq[mi] = *reinterpret_cast<const bf16x8*>(Ql + ((wv * 3 + mi) * 16 + l15) * QKPAD + l4 * 8);
  f32x4 s[3][9];
  #pragma unroll
  for (int mi = 0; mi < 3; ++mi)
    #pragma unroll
    for (int nt = 0; nt < 9; ++nt) s[mi][nt] = zz;
  #pragma unroll
  for (int nt = 0; nt < 9; ++nt){
    bf16x8 bk = *reinterpret_cast<const bf16x8*>(Kl + (nt * 16 + l15) * QKPAD + l4 * 8);
    #pragma unroll
    for (int mi = 0; mi < 3; ++mi)
      s[mi][nt] = __builtin_amdgcn_mfma_f32_16x16x32_bf16(aq[mi], bk, s[mi][nt], 0, 0, 0);
  }
  // add bias+mask (comb) then wave-parallel softmax (rows live in one 16-lane group)
  const u16* cb = comb + ((size_t)(b / WLON) * NH + h) * (NTOK * NTOK);
  #pragma unroll
  for (int mi = 0; mi < 3; ++mi){
    int i0 = (wv * 3 + mi) * 16 + l4 * 4;
    #pragma unroll
    for (int nt = 0; nt < 9; ++nt){
      int j = nt * 16 + l15;
      #pragma unroll
      for (int r = 0; r < 4; ++r)
        s[mi][nt][r] += b2f(cb[(i0 + r) * NTOK + j]);
    }
  }
  float invs[3][4];
  #pragma unroll
  for (int mi = 0; mi < 3; ++mi){
    #pragma unroll
    for (int r = 0; r < 4; ++r){
      float mx = -3.0e38f;
      #pragma unroll
      for (int nt = 0; nt < 9; ++nt) mx = fmaxf(mx, s[mi][nt][r]);
      #pragma unroll
      for (int off = 8; off; off >>= 1) mx = fmaxf(mx, __shfl_xor(mx, off, 16));
      float sum = 0.f;
      #pragma unroll
      for (int nt = 0; nt < 9; ++nt){
        float p = exp2f((s[mi][nt][r] - mx) * 1.4426950408889634f);
        s[mi][nt][r] = p; sum += p;
      }
      #pragma unroll
      for (int off = 8; off; off >>= 1) sum += __shfl_xor(sum, off, 16);
      invs[mi][r] = 1.0f / sum;   // applied at epilogue
    }
  }
  __syncthreads();   // everyone done reading Ql/Kl before Pl overwrites them

  // zero own rows' K-pad then write unnormalized P (bf16); PV reads only own rows -> no barrier
  for (int e = lane; e < 48 * 16; e += 64){
    int rr = e >> 4, c = 144 + (e & 15);
    Pl[(wv * 48 + rr) * VPPAD + c] = 0;
  }
  #pragma unroll
  for (int mi = 0; mi < 3; ++mi){
    int i0 = (wv * 3 + mi) * 16 + l4 * 4;
    #pragma unroll
    for (int nt = 0; nt < 9; ++nt){
      int j = nt * 16 + l15;
      #pragma unroll
      for (int r = 0; r < 4; ++r)
        Pl[(i0 + r) * VPPAD + j] = f2b(s[mi][nt][r]);
    }
  }
  // PV: out = P @ v  (K padded to 160 with exact zeros)
  f32x4 o[3][2];
  #pragma unroll
  for (int mi = 0; mi < 3; ++mi){ o[mi][0] = zz; o[mi][1] = zz; }
  #pragma unroll
  for (int kk = 0; kk < 5; ++kk){
    bf16x8 bv0 = *reinterpret_cast<const bf16x8*>(Vt + (l15) * VPPAD + kk * 32 + l4 * 8);
    bf16x8 bv1 = *reinterpret_cast<const bf16x8*>(Vt + (16 + l15) * VPPAD + kk * 32 + l4 * 8);
    #pragma unroll
    for (int mi = 0; mi < 3; ++mi){
      bf16x8 ap = *reinterpret_cast<const bf16x8*>(Pl + ((wv * 3 + mi) * 16 + l15) * VPPAD + kk * 32 + l4 * 8);
      o[mi][0] = __builtin_amdgcn_mfma_f32_16x16x32_bf16(ap, bv0, o[mi][0], 0, 0, 0);
      o[mi][1] = __builtin_amdgcn_mfma_f32_16x16x32_bf16(ap, bv1, o[mi][1], 0, 0, 0);
    }
  }
  // stash bf16 attn output into upper half of this row's d_out bytes (only proj block for
  // these rows reads it, and it stages before overwriting -> race-free)
  u16* stash = reinterpret_cast<u16*>(outbuf);
  #pragma unroll
  for (int mi = 0; mi < 3; ++mi){
    #pragma unroll
    for (int r = 0; r < 4; ++r){
      int i = (wv * 3 + mi) * 16 + l4 * 4 + r;
      size_t t = (size_t)b * NTOK + i;
      float is = invs[mi][r];
      #pragma unroll
      for (int nf = 0; nf < 2; ++nf){
        int ch = nf * 16 + l15;
        stash[t * 384 + 192 + h * CH + ch] = f2b(o[mi][nf][r] * is);
      }
    }
  }
}

// ---------------- K3: out = attn_out @ w2 + b2 (reads bf16 stash from d_out, writes fp32 d_out)
extern "C" __global__ __launch_bounds__(256) void proj_gemm(
    const u16* __restrict__ w2t, const float* __restrict__ b2, float* outbuf){
  __shared__ u16 Al[128 * APAD];
  __shared__ u16 Bl[64 * APAD];
  const int tid = threadIdx.x;
  const size_t row0 = (size_t)blockIdx.x * 128;
  const u16* stash = reinterpret_cast<const u16*>(outbuf);
  { // stage A from stash (already bf16)
    int r = tid >> 1, half = tid & 1;
    const u16* src = stash + (row0 + r) * 384 + 192 + half * 96;
    u16* dst = Al + r * APAD + half * 96;
    #pragma unroll
    for (int i = 0; i < 96; i += 8)
      *reinterpret_cast<uint4*>(dst + i) = *reinterpret_cast<const uint4*>(src + i);
  }
  const int wid = tid >> 6, lane = tid & 63;
  const int wm = (wid >> 1) * 64, wn = (wid & 1) * 32;
  const int l15 = lane & 15, l4 = lane >> 4;
  const f32x4 zz = {0.f, 0.f, 0.f, 0.f};

  for (int nt = 0; nt < 3; ++nt){
    __syncthreads();
    {
      int r = tid >> 2, qq = tid & 3;
      const u16* src = w2t + (size_t)(nt * 64 + r) * CDIM + qq * 48;
      u16* dst = Bl + r * APAD + qq * 48;
      #pragma unroll
      for (int i = 0; i < 48; i += 8)
        *reinterpret_cast<uint4*>(dst + i) = *reinterpret_cast<const uint4*>(src + i);
    }
    __syncthreads();

    f32x4 acc[4][2];
    #pragma unroll
    for (int mf = 0; mf < 4; ++mf){ acc[mf][0] = zz; acc[mf][1] = zz; }
    #pragma unroll
    for (int kk = 0; kk < 6; ++kk){
      bf16x8 av[4], bv[2];
      #pragma unroll
      for (int mf = 0; mf < 4; ++mf)
        av[mf] = *reinterpret_cast<const bf16x8*>(Al + (wm + mf * 16 + l15) * APAD + kk * 32 + l4 * 8);
      #pragma unroll
      for (int nf = 0; nf < 2; ++nf)
        bv[nf] = *reinterpret_cast<const bf16x8*>(Bl + (wn + nf * 16 + l15) * APAD + kk * 32 + l4 * 8);
      #pragma unroll
      for (int mf = 0; mf < 4; ++mf)
        #pragma unroll
        for (int nf = 0; nf < 2; ++nf)
          acc[mf][nf] = __builtin_amdgcn_mfma_f32_16x16x32_bf16(av[mf], bv[nf], acc[mf][nf], 0, 0, 0);
    }
    #pragma unroll
    for (int mf = 0; mf < 4; ++mf){
      #pragma unroll
      for (int r = 0; r < 4; ++r){
        size_t t = row0 + wm + mf * 16 + l4 * 4 + r;
        #pragma unroll
        for (int nf = 0; nf < 2; ++nf){
          int c = nt * 64 + wn + nf * 16 + l15;
          outbuf[t * CDIM + c] = acc[mf][nf][r] + b2[c];
        }
      }
    }
  }
}

extern "C" void kernel_launch(void* const* d_in, const int* in_sizes, int n_in,
                              void* d_out, int out_size, void* d_ws, size_t ws_size,
                              hipStream_t stream){
  const float* x    = (const float*)d_in[0];
  const float* w1   = (const float*)d_in[1];
  const float* b1   = (const float*)d_in[2];
  const float* w2   = (const float*)d_in[3];
  const float* b2   = (const float*)d_in[4];
  const float* bt   = (const float*)d_in[5];
  const float* mask = (const float*)d_in[6];
  const int*   pidx = (const int*)d_in[7];
  (void)in_sizes; (void)n_in; (void)out_size; (void)ws_size;

  char* ws = (char*)d_ws;
  u16* w1t  = (u16*)(ws + OFF_W1T);
  u16* w2t  = (u16*)(ws + OFF_W2T);
  u16* comb = (u16*)(ws + OFF_COMB);
  u16* qw   = (u16*)(ws + OFF_Q);
  u16* kw   = (u16*)(ws + OFF_K);
  u16* vw   = (u16*)(ws + OFF_V);
  float* out = (float*)d_out;

  prep_weights<<<dim3(432), dim3(256), 0, stream>>>(w1, w2, w1t, w2t);
  prep_comb<<<dim3(384, 81), dim3(256), 0, stream>>>(bt, mask, pidx, comb);
  qkv_gemm<<<dim3(1080), dim3(256), 0, stream>>>(x, w1t, b1, qw, kw, vw);
  attn_kernel<<<dim3(5760), dim3(192), 0, stream>>>(qw, kw, vw, comb, out);
  proj_gemm<<<dim3(1080), dim3(256), 0, stream>>>(w2t, b2, out);
}

// Round 2
// 347.768 us; speedup vs baseline: 1.1297x; 1.1297x over previous
//
#include <hip/hip_runtime.h>

typedef __attribute__((ext_vector_type(8))) short bf16x8;
typedef __attribute__((ext_vector_type(4))) float f32x4;
typedef unsigned short u16;
typedef unsigned int u32;

#define NTOK 144
#define CDIM 192
#define NH 6
#define CH 32
#define C3 576
#define NWIN 64
#define WLON 15
#define SCALE 0.17677669529663687f
#define LOG2E 1.4426950408889634f

// ws layout (bytes)
#define OFF_W1T  0u            // 576*192*2 = 221184
#define OFF_W2T  221184u       // 192*192*2 = 73728
#define OFF_COMB 294912u       // 384*81*64*4*2 = 15925248 (frag layout)
#define OFF_Q    16220160u     // 960*6*144*32*2 = 53084160
#define OFF_K    69304320u
#define OFF_V    122388480u    // stored transposed: [b][h][ch][144]

__device__ __forceinline__ u16 f2b(float f){
  u32 u = __float_as_uint(f);
  u32 r = u + 0x7FFFu + ((u >> 16) & 1u);   // RNE
  return (u16)(r >> 16);
}
__device__ __forceinline__ float b2f(u16 u){
  return __uint_as_float(((u32)u) << 16);
}
__device__ __forceinline__ u32 pk2(float a, float b){
  return (u32)f2b(a) | ((u32)f2b(b) << 16);
}

// ---------------- prep: transpose weights to bf16 (B-operand wants k-contiguous rows)
extern "C" __global__ __launch_bounds__(256) void prep_weights(
    const float* __restrict__ w1, const float* __restrict__ w2,
    u16* __restrict__ w1t, u16* __restrict__ w2t){
  int idx = blockIdx.x * 256 + threadIdx.x;
  if (idx < CDIM * C3){ int k = idx / C3;  int c = idx - k * C3;  w1t[c * CDIM + k] = f2b(w1[idx]); }
  if (idx < CDIM * CDIM){ int k = idx / CDIM; int c = idx - k * CDIM; w2t[c * CDIM + k] = f2b(w2[idx]); }
}

// ---------------- prep: comb in MFMA C-fragment layout:
// comb[nwh][ti(9)][nt(9)][lane(64)][r(4)] = bias_table[pidx[i*144+j]][nw][h] + mask[nw*15][i][j]
// where i = ti*16 + (lane>>4)*4 + r, j = nt*16 + (lane&15). attn reads one uint2 per tile per lane.
extern "C" __global__ __launch_bounds__(192) void prep_comb(
    const float* __restrict__ bt, const float* __restrict__ mask,
    const int* __restrict__ pidx, u16* __restrict__ comb){
  int nwh = blockIdx.x;                 // 0..383 = nw*6+h
  int nw = nwh / NH, h = nwh - nw * NH;
  int tl = blockIdx.y * 192 + threadIdx.x;   // 0..5183 = (ti*9+nt)*64+lane
  int ti = tl / 576;
  int rem = tl - ti * 576;
  int nt = rem >> 6, lane = rem & 63;
  int ib = ti * 16 + ((lane >> 4) << 2);
  int j  = nt * 16 + (lane & 15);
  const float* mrow = mask + (size_t)(nw * WLON) * (NTOK * NTOK);
  float v[4];
  #pragma unroll
  for (int r = 0; r < 4; ++r){
    int e = (ib + r) * NTOK + j;
    int pi = pidx[e];
    v[r] = bt[((size_t)pi * NWIN + nw) * NH + h] + mrow[e];
  }
  uint2 out; out.x = pk2(v[0], v[1]); out.y = pk2(v[2], v[3]);
  *reinterpret_cast<uint2*>(comb + ((size_t)nwh * 5184 + tl) * 4) = out;
}

// ---------------- K1: qkv = x @ w1 + b1 ; scatter q*scale,k -> [b][h][n][32]; v -> [b][h][32][144]
#define APAD 200
extern "C" __global__ __launch_bounds__(256) void qkv_gemm(
    const float* __restrict__ x, const u16* __restrict__ w1t, const float* __restrict__ b1,
    u16* __restrict__ qw, u16* __restrict__ kw, u16* __restrict__ vw){
  __shared__ u16 Al[128 * APAD];
  __shared__ u16 Bl[64 * APAD];
  const int tid = threadIdx.x;
  const size_t row0 = (size_t)blockIdx.x * 128;

  { // stage A: 128x192 fp32 -> bf16, 2 threads/row
    int r = tid >> 1, half = tid & 1;
    const float* src = x + (row0 + r) * CDIM + half * 96;
    u16* dst = Al + r * APAD + half * 96;
    #pragma unroll
    for (int i = 0; i < 96; i += 8){
      float4 f0 = *reinterpret_cast<const float4*>(src + i);
      float4 f1 = *reinterpret_cast<const float4*>(src + i + 4);
      uint4 pk; pk.x = pk2(f0.x, f0.y); pk.y = pk2(f0.z, f0.w);
      pk.z = pk2(f1.x, f1.y); pk.w = pk2(f1.z, f1.w);
      *reinterpret_cast<uint4*>(dst + i) = pk;
    }
  }
  const int wid = tid >> 6, lane = tid & 63;
  const int wm = (wid >> 1) * 64, wn = (wid & 1) * 32;
  const int l15 = lane & 15, l4 = lane >> 4;
  const f32x4 zz = {0.f, 0.f, 0.f, 0.f};

  for (int nt = 0; nt < 9; ++nt){
    __syncthreads();       // Bl free (prev compute done); A visible on nt=0
    { // stage B: 64 rows of w1t (192 bf16 each), 4 threads/row
      int r = tid >> 2, qq = tid & 3;
      const u16* src = w1t + (size_t)(nt * 64 + r) * CDIM + qq * 48;
      u16* dst = Bl + r * APAD + qq * 48;
      #pragma unroll
      for (int i = 0; i < 48; i += 8)
        *reinterpret_cast<uint4*>(dst + i) = *reinterpret_cast<const uint4*>(src + i);
    }
    __syncthreads();

    f32x4 acc[4][2];
    #pragma unroll
    for (int mf = 0; mf < 4; ++mf){ acc[mf][0] = zz; acc[mf][1] = zz; }
    #pragma unroll
    for (int kk = 0; kk < 6; ++kk){
      bf16x8 av[4], bv[2];
      #pragma unroll
      for (int mf = 0; mf < 4; ++mf)
        av[mf] = *reinterpret_cast<const bf16x8*>(Al + (wm + mf * 16 + l15) * APAD + kk * 32 + l4 * 8);
      #pragma unroll
      for (int nf = 0; nf < 2; ++nf)
        bv[nf] = *reinterpret_cast<const bf16x8*>(Bl + (wn + nf * 16 + l15) * APAD + kk * 32 + l4 * 8);
      #pragma unroll
      for (int mf = 0; mf < 4; ++mf)
        #pragma unroll
        for (int nf = 0; nf < 2; ++nf)
          acc[mf][nf] = __builtin_amdgcn_mfma_f32_16x16x32_bf16(av[mf], bv[nf], acc[mf][nf], 0, 0, 0);
    }
    // epilogue: c -> (which, h, ch); q gets *scale (after +b1, matching reference)
    #pragma unroll
    for (int nf = 0; nf < 2; ++nf){
      int c = nt * 64 + wn + nf * 16 + l15;
      int which = c / CDIM;
      int rem = c - which * CDIM;
      int hh = rem >> 5, chh = rem & 31;
      float bias = b1[c];
      float mult = (which == 0) ? SCALE : 1.0f;
      u16* base = (which == 0) ? qw : ((which == 1) ? kw : vw);
      #pragma unroll
      for (int mf = 0; mf < 4; ++mf){
        #pragma unroll
        for (int r = 0; r < 4; ++r){
          int t = (int)row0 + wm + mf * 16 + l4 * 4 + r;
          int bwin = t / NTOK;
          int n = t - bwin * NTOK;
          float v = (acc[mf][nf][r] + bias) * mult;
          size_t addr = (which == 2)
            ? ((((size_t)bwin * NH + hh) * CH + chh) * NTOK + n)    // V transposed
            : ((((size_t)bwin * NH + hh) * NTOK + n) * CH + chh);   // Q/K row-major
          base[addr] = f2b(v);
        }
      }
    }
  }
}

// ---------------- K2: per (window, head) attention — no barriers, no staging LDS.
// Q/K/V fragments loaded directly from global (coalesced 16B/lane); per-wave 16x32
// P chunk buffer in LDS; stash bf16 result in upper half of d_out rows.
extern "C" __global__ __launch_bounds__(192, 4) void attn_kernel(
    const u16* __restrict__ qw, const u16* __restrict__ kw, const u16* __restrict__ vw,
    const u16* __restrict__ comb, float* __restrict__ outbuf){
  __shared__ u16 Pl[3][16][40];   // per-wave P chunk, pad 40 (80B rows -> 8 bank groups)
  const int tid = threadIdx.x;
  const int bh = blockIdx.x;
  const int b = bh / NH, h = bh - b * NH;
  const int wv = tid >> 6, lane = tid & 63, l15 = lane & 15, l4 = lane >> 4;
  const size_t qkbase = ((size_t)b * NH + h) * (NTOK * CH);
  const size_t vbase  = ((size_t)b * NH + h) * (CH * NTOK);
  const size_t cbase  = ((size_t)((b / WLON) * NH + h)) * (5184 * 4);  // u16 units
  u16* Pw = &Pl[wv][0][0];
  u16* stash = reinterpret_cast<u16*>(outbuf);
  const f32x4 zz = {0.f, 0.f, 0.f, 0.f};

  for (int mi = 0; mi < 3; ++mi){
    const int ti = wv * 3 + mi;
    // Q fragment: rows ti*16..+15, direct from global
    bf16x8 aq = *reinterpret_cast<const bf16x8*>(qw + qkbase + (ti * 16 + l15) * CH + l4 * 8);
    // S = q @ k^T : 9 single-shot MFMAs (K=32)
    f32x4 s[9];
    #pragma unroll
    for (int nt = 0; nt < 9; ++nt){
      bf16x8 bk = *reinterpret_cast<const bf16x8*>(kw + qkbase + (nt * 16 + l15) * CH + l4 * 8);
      s[nt] = __builtin_amdgcn_mfma_f32_16x16x32_bf16(aq, bk, zz, 0, 0, 0);
    }
    // bias+mask add: one coalesced uint2 per tile per lane (fragment-layout comb)
    #pragma unroll
    for (int nt = 0; nt < 9; ++nt){
      uint2 cc = *reinterpret_cast<const uint2*>(comb + cbase + ((size_t)(ti * 9 + nt) * 64 + lane) * 4);
      s[nt][0] += b2f((u16)(cc.x & 0xFFFF));
      s[nt][1] += b2f((u16)(cc.x >> 16));
      s[nt][2] += b2f((u16)(cc.y & 0xFFFF));
      s[nt][3] += b2f((u16)(cc.y >> 16));
    }
    // wave-parallel softmax: row i lives in a 16-lane group (one j per nt)
    float invs[4];
    #pragma unroll
    for (int r = 0; r < 4; ++r){
      float mx = s[0][r];
      #pragma unroll
      for (int nt = 1; nt < 9; ++nt) mx = fmaxf(mx, s[nt][r]);
      #pragma unroll
      for (int off = 8; off; off >>= 1) mx = fmaxf(mx, __shfl_xor(mx, off, 16));
      float sum = 0.f;
      #pragma unroll
      for (int nt = 0; nt < 9; ++nt){
        float p = exp2f((s[nt][r] - mx) * LOG2E);
        s[nt][r] = p; sum += p;
      }
      #pragma unroll
      for (int off = 8; off; off >>= 1) sum += __shfl_xor(sum, off, 16);
      invs[r] = 1.0f / sum;   // applied at stash
    }
    // PV in 32-wide K chunks through the per-wave LDS chunk buffer (no barriers: own data only)
    f32x4 o0 = zz, o1 = zz;
    #pragma unroll
    for (int kk = 0; kk < 5; ++kk){
      #pragma unroll
      for (int r = 0; r < 4; ++r){
        Pw[(l4 * 4 + r) * 40 + l15] = f2b(s[2 * kk][r]);
        if (kk < 4) Pw[(l4 * 4 + r) * 40 + 16 + l15] = f2b(s[2 * kk + 1][r]);
      }
      int j0 = kk * 32 + l4 * 8;
      int jc = (j0 < NTOK) ? j0 : 0;          // clamp tail address (stay in-bounds)
      bf16x8 ap = *reinterpret_cast<const bf16x8*>(Pw + l15 * 40 + l4 * 8);
      bf16x8 bv0 = *reinterpret_cast<const bf16x8*>(vw + vbase + (size_t)l15 * NTOK + jc);
      bf16x8 bv1 = *reinterpret_cast<const bf16x8*>(vw + vbase + (size_t)(16 + l15) * NTOK + jc);
      if (j0 >= NTOK) ap = bf16x8{0, 0, 0, 0, 0, 0, 0, 0};   // tail K=16: zero P side
      o0 = __builtin_amdgcn_mfma_f32_16x16x32_bf16(ap, bv0, o0, 0, 0, 0);
      o1 = __builtin_amdgcn_mfma_f32_16x16x32_bf16(ap, bv1, o1, 0, 0, 0);
    }
    // stash bf16 attn output into upper half of this row's d_out bytes (proj reads before overwrite)
    #pragma unroll
    for (int r = 0; r < 4; ++r){
      size_t t = (size_t)b * NTOK + ti * 16 + l4 * 4 + r;
      float is = invs[r];
      stash[t * 384 + 192 + h * CH + l15]      = f2b(o0[r] * is);
      stash[t * 384 + 192 + h * CH + 16 + l15] = f2b(o1[r] * is);
    }
  }
}

// ---------------- K3: out = attn_out @ w2 + b2 (reads bf16 stash from d_out, writes fp32 d_out)
extern "C" __global__ __launch_bounds__(256) void proj_gemm(
    const u16* __restrict__ w2t, const float* __restrict__ b2, float* outbuf){
  __shared__ u16 Al[128 * APAD];
  __shared__ u16 Bl[64 * APAD];
  const int tid = threadIdx.x;
  const size_t row0 = (size_t)blockIdx.x * 128;
  const u16* stash = reinterpret_cast<const u16*>(outbuf);
  { // stage A from stash (already bf16)
    int r = tid >> 1, half = tid & 1;
    const u16* src = stash + (row0 + r) * 384 + 192 + half * 96;
    u16* dst = Al + r * APAD + half * 96;
    #pragma unroll
    for (int i = 0; i < 96; i += 8)
      *reinterpret_cast<uint4*>(dst + i) = *reinterpret_cast<const uint4*>(src + i);
  }
  const int wid = tid >> 6, lane = tid & 63;
  const int wm = (wid >> 1) * 64, wn = (wid & 1) * 32;
  const int l15 = lane & 15, l4 = lane >> 4;
  const f32x4 zz = {0.f, 0.f, 0.f, 0.f};

  for (int nt = 0; nt < 3; ++nt){
    __syncthreads();
    {
      int r = tid >> 2, qq = tid & 3;
      const u16* src = w2t + (size_t)(nt * 64 + r) * CDIM + qq * 48;
      u16* dst = Bl + r * APAD + qq * 48;
      #pragma unroll
      for (int i = 0; i < 48; i += 8)
        *reinterpret_cast<uint4*>(dst + i) = *reinterpret_cast<const uint4*>(src + i);
    }
    __syncthreads();

    f32x4 acc[4][2];
    #pragma unroll
    for (int mf = 0; mf < 4; ++mf){ acc[mf][0] = zz; acc[mf][1] = zz; }
    #pragma unroll
    for (int kk = 0; kk < 6; ++kk){
      bf16x8 av[4], bv[2];
      #pragma unroll
      for (int mf = 0; mf < 4; ++mf)
        av[mf] = *reinterpret_cast<const bf16x8*>(Al + (wm + mf * 16 + l15) * APAD + kk * 32 + l4 * 8);
      #pragma unroll
      for (int nf = 0; nf < 2; ++nf)
        bv[nf] = *reinterpret_cast<const bf16x8*>(Bl + (wn + nf * 16 + l15) * APAD + kk * 32 + l4 * 8);
      #pragma unroll
      for (int mf = 0; mf < 4; ++mf)
        #pragma unroll
        for (int nf = 0; nf < 2; ++nf)
          acc[mf][nf] = __builtin_amdgcn_mfma_f32_16x16x32_bf16(av[mf], bv[nf], acc[mf][nf], 0, 0, 0);
    }
    #pragma unroll
    for (int mf = 0; mf < 4; ++mf){
      #pragma unroll
      for (int r = 0; r < 4; ++r){
        size_t t = row0 + wm + mf * 16 + l4 * 4 + r;
        #pragma unroll
        for (int nf = 0; nf < 2; ++nf){
          int c = nt * 64 + wn + nf * 16 + l15;
          outbuf[t * CDIM + c] = acc[mf][nf][r] + b2[c];
        }
      }
    }
  }
}

extern "C" void kernel_launch(void* const* d_in, const int* in_sizes, int n_in,
                              void* d_out, int out_size, void* d_ws, size_t ws_size,
                              hipStream_t stream){
  const float* x    = (const float*)d_in[0];
  const float* w1   = (const float*)d_in[1];
  const float* b1   = (const float*)d_in[2];
  const float* w2   = (const float*)d_in[3];
  const float* b2   = (const float*)d_in[4];
  const float* bt   = (const float*)d_in[5];
  const float* mask = (const float*)d_in[6];
  const int*   pidx = (const int*)d_in[7];
  (void)in_sizes; (void)n_in; (void)out_size; (void)ws_size;

  char* ws = (char*)d_ws;
  u16* w1t  = (u16*)(ws + OFF_W1T);
  u16* w2t  = (u16*)(ws + OFF_W2T);
  u16* comb = (u16*)(ws + OFF_COMB);
  u16* qw   = (u16*)(ws + OFF_Q);
  u16* kw   = (u16*)(ws + OFF_K);
  u16* vw   = (u16*)(ws + OFF_V);
  float* out = (float*)d_out;

  prep_weights<<<dim3(432), dim3(256), 0, stream>>>(w1, w2, w1t, w2t);
  prep_comb<<<dim3(384, 27), dim3(192), 0, stream>>>(bt, mask, pidx, comb);
  qkv_gemm<<<dim3(1080), dim3(256), 0, stream>>>(x, w1t, b1, qw, kw, vw);
  attn_kernel<<<dim3(5760), dim3(192), 0, stream>>>(qw, kw, vw, comb, out);
  proj_gemm<<<dim3(1080), dim3(256), 0, stream>>>(w2t, b2, out);
}